// Round 12
// baseline (9452.834 us; speedup 1.0000x reference)
//
#include <hip/hip_runtime.h>
#include <hip/hip_bf16.h>
#include <float.h>

#define SEQ   8192
#define INW   180
#define HID   64
#define G4    256   // 4*HID
#define OUTW  10
#define XW    318   // 10 + 64 + 180 + 64
#define WLDS_BYTES (3 * G4 * 32 * 4)   // 98304 = 96 KB packed fp16 weights

typedef _Float16 h16x2 __attribute__((ext_vector_type(2)));
typedef unsigned int uint32;

__device__ __forceinline__ float frcp(float x)   { return __builtin_amdgcn_rcpf(x); }
__device__ __forceinline__ float tanhf_f(float x){ return 1.0f - 2.0f * frcp(1.0f + __expf(2.0f * x)); }
__device__ __forceinline__ float gate_act(float x, bool isg) {
    float xx = isg ? 2.0f * x : x;
    float s  = frcp(1.0f + __expf(-xx));
    return isg ? 2.0f * s - 1.0f : s;
}

// v_dot2_f32_f16: acc += a.x*b.x + a.y*b.y  (f32 accumulate, exact products)
__device__ __forceinline__ float fdot2h(uint32 a, uint32 b, float c) {
#if __has_builtin(__builtin_amdgcn_fdot2)
    return __builtin_amdgcn_fdot2(__builtin_bit_cast(h16x2, a),
                                  __builtin_bit_cast(h16x2, b), c, false);
#else
    asm("v_dot2_f32_f16 %0, %1, %2, %3" : "=v"(c) : "v"(a), "v"(b), "0"(c));
    return c;
#endif
}

__device__ __forceinline__ uint32 pack_h2(float lo, float hi) {
    h16x2 h; h.x = (_Float16)lo; h.y = (_Float16)hi;
    return __builtin_bit_cast(uint32, h);
}

// ---------------------------------------------------------------------------
// Kernel 0: pack the 3 recurrent matrices to half2 (pairs along K), row-major.
// ---------------------------------------------------------------------------
__global__ __launch_bounds__(256) void k_packw(
    const float* __restrict__ Whh0, const float* __restrict__ Wih1,
    const float* __restrict__ Whh1,
    uint32* __restrict__ w0h, uint32* __restrict__ w1ah, uint32* __restrict__ w1bh)
{
    const int gid = blockIdx.x * 256 + threadIdx.x;   // 0 .. 3*8192-1
    const int mat = gid >> 13;
    const int i   = gid & 8191;
    const int r   = i >> 5, k2 = i & 31;
    const float* S = (mat == 0) ? Whh0 : (mat == 1) ? Wih1 : Whh1;
    uint32*      D = (mat == 0) ? w0h  : (mat == 1) ? w1ah : w1bh;
    D[i] = pack_h2(S[r * 64 + 2 * k2], S[r * 64 + 2 * k2 + 1]);
}

// ---------------------------------------------------------------------------
// Kernel 1: pre[s][t] = x[s] @ Wih0[row(t)].T + bih0 + bhh0  (f32)
// row(t) = ((t&63)>>4)*64 + (t>>6)*16 + (t&15)  — matches k_lstm_seq mapping
// ---------------------------------------------------------------------------
#define PRE_TS 16
__global__ __launch_bounds__(256) void k_precompute(
    const float* __restrict__ x, const float* __restrict__ Wih0,
    const float* __restrict__ bih0, const float* __restrict__ bhh0,
    float* __restrict__ pre)
{
    __shared__ float xT[INW][PRE_TS];
    const int t  = threadIdx.x;
    const int rr = ((t & 63) >> 4) * 64 + (t >> 6) * 16 + (t & 15);
    const int s0 = blockIdx.x * PRE_TS;
    for (int i = t; i < PRE_TS * INW; i += 256) {
        int s = i / INW, k = i % INW;
        xT[k][s] = x[s0 * INW + i];
    }
    __syncthreads();
    float acc[PRE_TS];
    const float b = bih0[rr] + bhh0[rr];
#pragma unroll
    for (int s = 0; s < PRE_TS; ++s) acc[s] = b;
    for (int k = 0; k < INW; ++k) {
        float w = Wih0[rr * INW + k];
#pragma unroll
        for (int s = 0; s < PRE_TS; ++s) acc[s] += w * xT[k][s];
    }
#pragma unroll
    for (int s = 0; s < PRE_TS; ++s) pre[(s0 + s) * G4 + t] = acc[s];
}

// 4 fdot2 over one weight quad (uint4 = 4 half2) vs one h quad
#define DOT4(A0, A1, A2, A3, WQ, HQ)                         \
    A0 = fdot2h((WQ).x, (HQ).x, A0);                         \
    A1 = fdot2h((WQ).y, (HQ).y, A1);                         \
    A2 = fdot2h((WQ).z, (HQ).z, A2);                         \
    A3 = fdot2h((WQ).w, (HQ).w, A3);

// full row dot from swizzled LDS (WL) vs broadcast h (HP); e = r&7
#define DOT8L(A0, A1, A2, A3, WL, e, HP)                     \
    {                                                        \
        uint4 w0 = (WL)[0 ^ (e)], w1 = (WL)[1 ^ (e)];        \
        uint4 w2 = (WL)[2 ^ (e)], w3 = (WL)[3 ^ (e)];        \
        uint4 h0 = (HP)[0], h1 = (HP)[1], h2 = (HP)[2], h3 = (HP)[3]; \
        DOT4(A0, A1, A2, A3, w0, h0)                         \
        DOT4(A0, A1, A2, A3, w1, h1)                         \
        DOT4(A0, A1, A2, A3, w2, h2)                         \
        DOT4(A0, A1, A2, A3, w3, h3)                         \
    }                                                        \
    __builtin_amdgcn_sched_barrier(0);                       \
    {                                                        \
        uint4 w4 = (WL)[4 ^ (e)], w5 = (WL)[5 ^ (e)];        \
        uint4 w6 = (WL)[6 ^ (e)], w7 = (WL)[7 ^ (e)];        \
        uint4 h4 = (HP)[4], h5 = (HP)[5], h6 = (HP)[6], h7 = (HP)[7]; \
        DOT4(A0, A1, A2, A3, w4, h4)                         \
        DOT4(A0, A1, A2, A3, w5, h5)                         \
        DOT4(A0, A1, A2, A3, w6, h6)                         \
        DOT4(A0, A1, A2, A3, w7, h7)                         \
    }

// gate combine: a = own gate value; lanes g*16+usub; returns via refs
#define GATE_COMBINE(a, g, i_, f_, gg_, o_)                  \
    float x16 = __shfl_xor((a), 16);                         \
    float x32 = __shfl_xor((a), 32);                         \
    float x48 = __shfl_xor(x16, 32);                         \
    {                                                        \
        bool b0 = ((g) & 1) != 0, b1 = ((g) & 2) != 0;       \
        float m01 = b0 ? x16 : (a);                          \
        float m23 = b0 ? x48 : x32;                          \
        float p01 = b0 ? (a) : x16;                          \
        float p23 = b0 ? x32 : x48;                          \
        i_  = b1 ? m23 : m01;                                \
        f_  = b1 ? p23 : p01;                                \
        gg_ = b1 ? m01 : m23;                                \
        o_  = b1 ? p01 : p23;                                \
    }

// ---------------------------------------------------------------------------
// Kernel 2: serial 2-layer LSTM, LDS-resident fp16 weights (96 KB dynamic).
// ONE block, 768 threads (12 waves). Weight storage: R4-R11 proved the
// register allocator spills ANY long-lived per-thread array here (granted
// VGPR 36-76 across all configs/attributes), forcing a ~96B/cyc scratch
// re-stream. LDS gives 256B/cyc deterministically.
//   grp0 (t<256):    Whh0 rows.  phase A: h0[s+1] = cell0(x[s], h0[s], c0)
//   grp2 (t>=512):   Whh1 rows.  phase A: partial[i8] = Whh1_r . h1[s-1]
//   grp1 (256..511): Wih1 rows.  phase B: z = Wih1_r.h0[s+1] + partial + b1
// Mapping: i8 = t&255, wave w = i8>>6, lane l = i8&63, g = l>>4,
//          u = w*16 + (l&15), row r = g*64+u.  8-lane b128 phase-groups then
//          carry 8 distinct (r&7) -> quad-swizzle slot = j4 ^ (r&7) is
//          bank-conflict-FREE (unswizzled row-major would be 16-way).
// ---------------------------------------------------------------------------
__global__ __launch_bounds__(768, 1)
void k_lstm_seq(
    const float* __restrict__ pre,
    const uint32* __restrict__ w0h,    // [G4][32] packed Whh0
    const uint32* __restrict__ w1ah,   // [G4][32] packed Wih1
    const uint32* __restrict__ w1bh,   // [G4][32] packed Whh1
    const float* __restrict__ bih1, const float* __restrict__ bhh1,
    float* __restrict__ oldh, float* __restrict__ h1h)
{
    extern __shared__ __attribute__((aligned(16))) uint32 dynw[];  // 3*8192 dwords

    const int t   = threadIdx.x;
    const int grp = t >> 8;           // 0: Whh0, 1: Wih1, 2: Whh1
    const int i8  = t & 255;
    const int w   = i8 >> 6;          // wave-in-group: units w*16..w*16+15
    const int l   = i8 & 63;
    const int g   = l >> 4;           // gate: 0=i 1=f 2=g 3=o
    const int u   = w * 16 + (l & 15);
    const int r   = g * 64 + u;       // weight row
    const int e   = r & 7;            // swizzle key
    const bool isg = (g == 2);

    __shared__ __attribute__((aligned(16))) uint32 h0p[2][32];
    __shared__ __attribute__((aligned(16))) uint32 h1p[2][32];
    __shared__ float partial[256];
    if (t < 32) { h0p[0][t] = 0u; h0p[1][t] = 0u; h1p[0][t] = 0u; h1p[1][t] = 0u; }
    if (t < 64) oldh[t] = 0.0f;

    // ---- stage this thread's weight row into swizzled LDS (once) ----
    uint4* WL;
    {
        const uint32* Wsrc = (grp == 0) ? w0h : (grp == 1) ? w1ah : w1bh;
        const uint4* Wg = (const uint4*)(Wsrc + r * 32);
        WL = (uint4*)(dynw + grp * 8192 + r * 32);
#pragma unroll
        for (int j4 = 0; j4 < 8; ++j4) WL[j4 ^ e] = Wg[j4];
    }
    const float b1 = (grp == 1) ? (bih1[r] + bhh1[r]) : 0.0f;
    float cc = 0.0f;                          // c0 (grp0) / c1 (grp1)
    float preval = (grp == 0) ? pre[i8] : 0.0f;
    __syncthreads();

    for (int s = 0; s < SEQ; ++s) {
        const int p = s & 1, pn = p ^ 1;

        // ================= phase A =================
        if (grp == 0) {
            const int sn = (s + 1 < SEQ) ? (s + 1) : s;
            float prenext = pre[sn * G4 + i8];

            const uint4* Hp = (const uint4*)&h0p[p][0];      // h0[s]
            float a0 = preval, a1 = 0.f, a2 = 0.f, a3 = 0.f;
            DOT8L(a0, a1, a2, a3, WL, e, Hp)
            float a = gate_act((a0 + a1) + (a2 + a3), isg);
            float i_, f_, gg_, o_;
            GATE_COMBINE(a, g, i_, f_, gg_, o_)
            cc = fmaf(f_, cc, i_ * gg_);
            float h0n = o_ * tanhf_f(cc);
            float hp  = __shfl_xor(h0n, 1);                  // unit u^1
            if ((l & 49) == 0) h0p[pn][u >> 1] = pack_h2(h0n, hp); // g=0, even u
            if ((l >> 4) == 1 && s + 1 < SEQ) oldh[(s + 1) * HID + u] = h0n; // g=1 lanes
            preval = prenext;
        } else if (grp == 2) {
            const uint4* Hp = (const uint4*)&h1p[p][0];      // h1[s-1]
            float a0 = 0.f, a1 = 0.f, a2 = 0.f, a3 = 0.f;
            DOT8L(a0, a1, a2, a3, WL, e, Hp)
            partial[i8] = (a0 + a1) + (a2 + a3);
        }
        asm volatile("s_waitcnt lgkmcnt(0)" ::: "memory");
        __builtin_amdgcn_s_barrier();
        asm volatile("" ::: "memory");

        // ================= phase B =================
        if (grp == 1) {
            const uint4* Hp = (const uint4*)&h0p[pn][0];     // h0[s+1] (new)
            float a0 = b1, a1 = 0.f, a2 = 0.f, a3 = 0.f;
            DOT8L(a0, a1, a2, a3, WL, e, Hp)
            float z = ((a0 + a1) + (a2 + a3)) + partial[i8];
            float a = gate_act(z, isg);
            float i_, f_, gg_, o_;
            GATE_COMBINE(a, g, i_, f_, gg_, o_)
            cc = fmaf(f_, cc, i_ * gg_);
            float h1n = o_ * tanhf_f(cc);
            float hp  = __shfl_xor(h1n, 1);                  // unit u^1
            if ((l & 49) == 0) h1p[pn][u >> 1] = pack_h2(h1n, hp);
            if ((l >> 4) == 1) h1h[s * HID + u] = h1n;
        }
        asm volatile("s_waitcnt lgkmcnt(0)" ::: "memory");
        __builtin_amdgcn_s_barrier();
        asm volatile("" ::: "memory");
    }
}

// ---------------------------------------------------------------------------
// Kernel 3a/3b: column-wise min/max of oldh (64 cols x 8192 rows)
// ---------------------------------------------------------------------------
__global__ __launch_bounds__(256) void k_minmax1(
    const float* __restrict__ oldh, float* __restrict__ pmn, float* __restrict__ pmx)
{
    const int t = threadIdx.x, b = blockIdx.x;
    float vmn = FLT_MAX, vmx = -FLT_MAX;
    for (int i = t; i < 128 * HID; i += 256) {
        float v = oldh[b * 128 * HID + i];
        vmn = fminf(vmn, v); vmx = fmaxf(vmx, v);
    }
    __shared__ float smn[256], smx[256];
    smn[t] = vmn; smx[t] = vmx;
    __syncthreads();
    if (t < 64) {
        float m0 = fminf(fminf(smn[t], smn[t + 64]), fminf(smn[t + 128], smn[t + 192]));
        float m1 = fmaxf(fmaxf(smx[t], smx[t + 64]), fmaxf(smx[t + 128], smx[t + 192]));
        pmn[b * 64 + t] = m0; pmx[b * 64 + t] = m1;
    }
}

__global__ __launch_bounds__(256) void k_minmax2(
    const float* __restrict__ pmn, const float* __restrict__ pmx,
    float* __restrict__ mn, float* __restrict__ mx)
{
    const int t = threadIdx.x, col = t & 63, chunk = t >> 6;
    float vmn = FLT_MAX, vmx = -FLT_MAX;
    for (int r = chunk * 16; r < chunk * 16 + 16; ++r) {
        vmn = fminf(vmn, pmn[r * 64 + col]);
        vmx = fmaxf(vmx, pmx[r * 64 + col]);
    }
    __shared__ float smn[256], smx[256];
    smn[t] = vmn; smx[t] = vmx;
    __syncthreads();
    if (t < 64) {
        mn[t] = fminf(fminf(smn[t], smn[t + 64]), fminf(smn[t + 128], smn[t + 192]));
        mx[t] = fmaxf(fmaxf(smx[t], smx[t + 64]), fmaxf(smx[t + 128], smx[t + 192]));
    }
}

// ---------------------------------------------------------------------------
// Kernel 4: per-row head + HPM MLP fwd + closed-form VJP. 1 wave per row.
// ---------------------------------------------------------------------------
__global__ __launch_bounds__(256) void k_finalize(
    const float* __restrict__ h1h, const float* __restrict__ oldh,
    const float* __restrict__ x,
    const float* __restrict__ Wlin, const float* __restrict__ blin,
    const float* __restrict__ Wh1,  const float* __restrict__ bh1,
    const float* __restrict__ Wh2,  const float* __restrict__ bh2,
    const float* __restrict__ mn,   const float* __restrict__ mx,
    float* __restrict__ dout)
{
    float* out_o = dout;                          // [SEQ][10]
    float* out_F = dout + SEQ * OUTW;             // [SEQ][180]
    float* out_A = dout + SEQ * (OUTW + INW);     // [SEQ][318]

    const int wave = threadIdx.x >> 6, lane = threadIdx.x & 63;
    const int row  = blockIdx.x * 4 + wave;

    __shared__ float Xs[4][XW + 2];
    __shared__ float h1sh[4][HID];

    h1sh[wave][lane] = h1h[row * HID + lane];
    float mnv = mn[lane], mxv = mx[lane];
    Xs[wave][254 + lane] = (oldh[row * HID + lane] - mnv) * frcp(mxv - mnv + 1e-6f);
    Xs[wave][10 + lane]  = 0.0f;
    for (int c = lane; c < INW; c += 64) Xs[wave][74 + c] = x[row * INW + c];
    __syncthreads();

    if (lane < OUTW) {
        float o = blin[lane];
#pragma unroll
        for (int k = 0; k < HID; ++k) o += Wlin[lane * HID + k] * h1sh[wave][k];
        Xs[wave][lane] = o;
        out_o[row * OUTW + lane] = o;
    }
    __syncthreads();

    float z0 = 0.f, z1 = 0.f, s0 = 0.f, s1 = 0.f;
    for (int c = lane; c < XW; c += 64) {
        float xv = Xs[wave][c];
        z0 += xv * Wh1[c];
        z1 += xv * Wh1[XW + c];
    }
    for (int j = lane; j < INW; j += 64) {
        s0 += Wh2[j * 2 + 0];
        s1 += Wh2[j * 2 + 1];
    }
#pragma unroll
    for (int off = 32; off; off >>= 1) {
        z0 += __shfl_xor(z0, off); z1 += __shfl_xor(z1, off);
        s0 += __shfl_xor(s0, off); s1 += __shfl_xor(s1, off);
    }
    const float t0 = tanhf_f(z0 + bh1[0]);
    const float t1 = tanhf_f(z1 + bh1[1]);
    const float a0 = -s0 * (1.0f - t0 * t0);
    const float a1 = -s1 * (1.0f - t1 * t1);

    for (int c = lane; c < INW; c += 64)
        out_F[row * INW + c] = -(t0 * Wh2[c * 2 + 0] + t1 * Wh2[c * 2 + 1] + bh2[c]);
    for (int c = lane; c < XW; c += 64)
        out_A[row * XW + c] = a0 * Wh1[c] + a1 * Wh1[XW + c];
}

// ---------------------------------------------------------------------------
extern "C" void kernel_launch(void* const* d_in, const int* in_sizes, int n_in,
                              void* d_out, int out_size, void* d_ws, size_t ws_size,
                              hipStream_t stream)
{
    const float* input = (const float*)d_in[0];
    const float* Wih0  = (const float*)d_in[1];
    const float* Whh0  = (const float*)d_in[2];
    const float* bih0  = (const float*)d_in[3];
    const float* bhh0  = (const float*)d_in[4];
    const float* Wih1  = (const float*)d_in[5];
    const float* Whh1  = (const float*)d_in[6];
    const float* bih1  = (const float*)d_in[7];
    const float* bhh1  = (const float*)d_in[8];
    const float* Wlin  = (const float*)d_in[9];
    const float* blin  = (const float*)d_in[10];
    const float* Wh1   = (const float*)d_in[11];
    const float* bh1   = (const float*)d_in[12];
    const float* Wh2   = (const float*)d_in[13];
    const float* bh2   = (const float*)d_in[14];

    float* ws   = (float*)d_ws;
    float* pre  = ws;                         // SEQ*G4
    float* oldh = pre  + SEQ * G4;            // SEQ*HID
    float* h1h  = oldh + SEQ * HID;           // SEQ*HID
    float* pmn  = h1h  + SEQ * HID;           // 64*64
    float* pmx  = pmn  + 64 * 64;             // 64*64
    float* mn   = pmx  + 64 * 64;             // 64
    float* mx   = mn   + 64;                  // 64
    uint32* w0h  = (uint32*)(mx + 64);        // G4*32 packed half2
    uint32* w1ah = w0h  + G4 * 32;
    uint32* w1bh = w1ah + G4 * 32;
    float* out  = (float*)d_out;

    // allow 96 KB dynamic LDS for the recurrence kernel (idempotent,
    // not a stream op -> graph-capture safe)
    (void)hipFuncSetAttribute((const void*)k_lstm_seq,
                              hipFuncAttributeMaxDynamicSharedMemorySize,
                              WLDS_BYTES);

    hipLaunchKernelGGL(k_packw, dim3(96), dim3(256), 0, stream,
                       Whh0, Wih1, Whh1, w0h, w1ah, w1bh);
    hipLaunchKernelGGL(k_precompute, dim3(SEQ / PRE_TS), dim3(256), 0, stream,
                       input, Wih0, bih0, bhh0, pre);
    hipLaunchKernelGGL(k_lstm_seq, dim3(1), dim3(768), WLDS_BYTES, stream,
                       pre, w0h, w1ah, w1bh, bih1, bhh1, oldh, h1h);
    hipLaunchKernelGGL(k_minmax1, dim3(64), dim3(256), 0, stream, oldh, pmn, pmx);
    hipLaunchKernelGGL(k_minmax2, dim3(1), dim3(256), 0, stream, pmn, pmx, mn, mx);
    hipLaunchKernelGGL(k_finalize, dim3(SEQ / 4), dim3(256), 0, stream,
                       h1h, oldh, input, Wlin, blin, Wh1, bh1, Wh2, bh2, mn, mx, out);
}

// Round 13
// 6364.658 us; speedup vs baseline: 1.4852x; 1.4852x over previous
//
#include <hip/hip_runtime.h>
#include <hip/hip_bf16.h>
#include <float.h>

#define SEQ   8192
#define INW   180
#define HID   64
#define G4    256   // 4*HID
#define OUTW  10
#define XW    318   // 10 + 64 + 180 + 64

typedef float f32x4 __attribute__((ext_vector_type(4)));
typedef _Float16 h16x2 __attribute__((ext_vector_type(2)));
typedef unsigned int uint32;

__device__ __forceinline__ float frcp(float x)   { return __builtin_amdgcn_rcpf(x); }
__device__ __forceinline__ float tanhf_f(float x){ return 1.0f - 2.0f * frcp(1.0f + __expf(2.0f * x)); }
__device__ __forceinline__ float gate_act(float x, bool isg) {
    float xx = isg ? 2.0f * x : x;
    float s  = frcp(1.0f + __expf(-xx));
    return isg ? 2.0f * s - 1.0f : s;
}

template<int CTRL>
__device__ __forceinline__ float dpp_bcast(float x) {
    return __int_as_float(__builtin_amdgcn_update_dpp(
        0, __float_as_int(x), CTRL, 0xF, 0xF, true));
}

// v_dot2_f32_f16: acc += a.x*b.x + a.y*b.y  (f32 accumulate, exact products)
__device__ __forceinline__ float fdot2h(uint32 a, uint32 b, float c) {
#if __has_builtin(__builtin_amdgcn_fdot2)
    return __builtin_amdgcn_fdot2(__builtin_bit_cast(h16x2, a),
                                  __builtin_bit_cast(h16x2, b), c, false);
#else
    asm("v_dot2_f32_f16 %0, %1, %2, %3" : "=v"(c) : "v"(a), "v"(b), "0"(c));
    return c;
#endif
}

__device__ __forceinline__ uint32 pack_h2(float lo, float hi) {
    h16x2 h; h.x = (_Float16)lo; h.y = (_Float16)hi;
    return __builtin_bit_cast(uint32, h);
}

// ---- AGPR parking: the VGPR allocator refuses >~68 regs here (R4-R12),
// but AGPRs are a separately-accounted bank of the gfx950 unified file.
// "a"-constrained asm values must be AGPR-allocated; weights parked once,
// read back per use (1 VALU each) — no scratch re-stream.
__device__ __forceinline__ void agpr_write(float& dst, uint32 v) {
    asm volatile("v_accvgpr_write_b32 %0, %1" : "=a"(dst) : "v"(v));
}
__device__ __forceinline__ uint32 agpr_read(const float& src) {
    uint32 v;
    asm("v_accvgpr_read_b32 %0, %1" : "=v"(v) : "a"(src));
    return v;
}

// ---------------------------------------------------------------------------
// Kernel 0: pack the 3 recurrent matrices to half2 (pairs along K).
// ---------------------------------------------------------------------------
__global__ __launch_bounds__(256) void k_packw(
    const float* __restrict__ Whh0, const float* __restrict__ Wih1,
    const float* __restrict__ Whh1,
    uint32* __restrict__ w0h, uint32* __restrict__ w1ah, uint32* __restrict__ w1bh)
{
    const int gid = blockIdx.x * 256 + threadIdx.x;   // 0 .. 3*8192-1
    const int mat = gid >> 13;
    const int i   = gid & 8191;
    const int r   = i >> 5, k2 = i & 31;
    const float* S = (mat == 0) ? Whh0 : (mat == 1) ? Wih1 : Whh1;
    uint32*      D = (mat == 0) ? w0h  : (mat == 1) ? w1ah : w1bh;
    D[i] = pack_h2(S[r * 64 + 2 * k2], S[r * 64 + 2 * k2 + 1]);
}

// ---------------------------------------------------------------------------
// Kernel 1: pre[s][t] = x[s] @ Wih0[row(t)].T + bih0[row(t)] + bhh0[row(t)]
// row(t) = (t&3)*64 + (t>>2)  (f32, unchanged — R9-verified)
// ---------------------------------------------------------------------------
#define PRE_TS 16
__global__ __launch_bounds__(256) void k_precompute(
    const float* __restrict__ x, const float* __restrict__ Wih0,
    const float* __restrict__ bih0, const float* __restrict__ bhh0,
    float* __restrict__ pre)
{
    __shared__ float xT[INW][PRE_TS];
    const int t  = threadIdx.x;
    const int rr = (t & 3) * 64 + (t >> 2);
    const int s0 = blockIdx.x * PRE_TS;
    for (int i = t; i < PRE_TS * INW; i += 256) {
        int s = i / INW, k = i % INW;
        xT[k][s] = x[s0 * INW + i];
    }
    __syncthreads();
    float acc[PRE_TS];
    const float b = bih0[rr] + bhh0[rr];
#pragma unroll
    for (int s = 0; s < PRE_TS; ++s) acc[s] = b;
    for (int k = 0; k < INW; ++k) {
        float w = Wih0[rr * INW + k];
#pragma unroll
        for (int s = 0; s < PRE_TS; ++s) acc[s] += w * xT[k][s];
    }
#pragma unroll
    for (int s = 0; s < PRE_TS; ++s) pre[(s0 + s) * G4 + t] = acc[s];
}

// 4 fdot2 over one weight quad (read from AGPR) vs one h quad
#define DOTQ_AG(A0, A1, A2, A3, AG, J, HQ)                   \
    A0 = fdot2h(agpr_read((AG)[4*(J)+0]), (HQ).x, A0);       \
    A1 = fdot2h(agpr_read((AG)[4*(J)+1]), (HQ).y, A1);       \
    A2 = fdot2h(agpr_read((AG)[4*(J)+2]), (HQ).z, A2);       \
    A3 = fdot2h(agpr_read((AG)[4*(J)+3]), (HQ).w, A3);

// ---------------------------------------------------------------------------
// Kernel 2: serial 2-layer LSTM, wave-specialized, AGPR-parked weights.
// ONE block, 512 threads (8 waves, 2/SIMD). SEQ+1 barrier intervals
// (R9-verified skew), one s_barrier per interval:
//   t <  256 (q=t):     layer0, s=0..SEQ-1: H0[s+1]=cell(x(s),H0[s],c0)
//                       Whh0 row = 32 AGPRs.
//   t >= 256 (q=t-256): layer1, s=1..SEQ:  Y[s-1]=cell(H0[s],Y[s-2],c1)
//                       Wih1 row + Whh1 row = 64 AGPRs.
// DPP quad gate-combine (q = 4u+g). h exchanged as packed half2 via LDS.
// ---------------------------------------------------------------------------
__global__ __launch_bounds__(512)
void k_lstm_seq(
    const float* __restrict__ pre,
    const uint32* __restrict__ w0h,    // [G4][32] packed Whh0
    const uint32* __restrict__ w1ah,   // [G4][32] packed Wih1
    const uint32* __restrict__ w1bh,   // [G4][32] packed Whh1
    const float* __restrict__ bih1, const float* __restrict__ bhh1,
    float* __restrict__ oldh, float* __restrict__ h1h)
{
    const int t = threadIdx.x;

    __shared__ __attribute__((aligned(16))) uint32 h0p[2][32];
    __shared__ __attribute__((aligned(16))) uint32 h1p[2][32];
    if (t < 32) { h0p[0][t] = 0u; h0p[1][t] = 0u; h1p[0][t] = 0u; h1p[1][t] = 0u; }
    if (t < 64) oldh[t] = 0.0f;
    __syncthreads();

    if (t < 256) {
        // ================= layer-0: 32 AGPR-parked dwords =================
        const int q = t, g = q & 3, u = q >> 2, r = g * 64 + u;
        const bool isg = (g == 2);

        float ag[32];
        {
            const uint4* W = (const uint4*)(w0h + r * 32);
#pragma unroll
            for (int j = 0; j < 8; ++j) {
                uint4 v = W[j];
                agpr_write(ag[4*j+0], v.x); agpr_write(ag[4*j+1], v.y);
                agpr_write(ag[4*j+2], v.z); agpr_write(ag[4*j+3], v.w);
            }
        }
        float c0 = 0.f;
        float preval = pre[q];
        for (int s = 0; s <= SEQ; ++s) {
            if (s < SEQ) {
                const int p = s & 1, pn = p ^ 1;
                const int sn = (s + 1 < SEQ) ? (s + 1) : s;
                float prenext = pre[sn * G4 + q];

                const uint4* Hp = (const uint4*)&h0p[p][0];
                float a0 = preval, a1 = 0.f, a2 = 0.f, a3 = 0.f;
#pragma unroll
                for (int j = 0; j < 8; ++j) {
                    uint4 hq = Hp[j];
                    DOTQ_AG(a0, a1, a2, a3, ag, j, hq)
                }
                float a  = gate_act((a0 + a1) + (a2 + a3), isg);
                float ai = dpp_bcast<0x00>(a);
                float af = dpp_bcast<0x55>(a);
                float agg= dpp_bcast<0xAA>(a);
                float ao = dpp_bcast<0xFF>(a);
                c0 = fmaf(af, c0, ai * agg);
                float h0n = ao * tanhf_f(c0);
                float hpart = __shfl_xor(h0n, 4);        // partner unit u^1
                if ((q & 7) == 0) h0p[pn][u >> 1] = pack_h2(h0n, hpart);
                if ((q & 3) == 1 && s + 1 < SEQ) oldh[(s + 1) * HID + u] = h0n;
                preval = prenext;
            }
            asm volatile("s_waitcnt lgkmcnt(0)" ::: "memory");
            __builtin_amdgcn_s_barrier();
            asm volatile("" ::: "memory");
        }
    } else {
        // ================= layer-1: 64 AGPR-parked dwords =================
        const int q = t - 256, g = q & 3, u = q >> 2, r = g * 64 + u;
        const bool isg = (g == 2);

        float ag[64];
        {
            const uint4* Wa = (const uint4*)(w1ah + r * 32);
            const uint4* Wb = (const uint4*)(w1bh + r * 32);
#pragma unroll
            for (int j = 0; j < 8; ++j) {
                uint4 v = Wa[j];
                agpr_write(ag[4*j+0], v.x); agpr_write(ag[4*j+1], v.y);
                agpr_write(ag[4*j+2], v.z); agpr_write(ag[4*j+3], v.w);
            }
#pragma unroll
            for (int j = 0; j < 8; ++j) {
                uint4 v = Wb[j];
                agpr_write(ag[32+4*j+0], v.x); agpr_write(ag[32+4*j+1], v.y);
                agpr_write(ag[32+4*j+2], v.z); agpr_write(ag[32+4*j+3], v.w);
            }
        }
        const float b1 = bih1[r] + bhh1[r];
        float c1 = 0.f;
        for (int s = 0; s <= SEQ; ++s) {
            if (s >= 1) {
                const int p = s & 1, pn = p ^ 1;
                const uint4* H0 = (const uint4*)&h0p[p][0];   // H0[s]
                const uint4* H1 = (const uint4*)&h1p[p][0];   // Y[s-2]
                float a0 = b1, a1 = 0.f, a2 = 0.f, a3 = 0.f;
#pragma unroll
                for (int j = 0; j < 8; ++j) {
                    uint4 hq = H0[j];
                    DOTQ_AG(a0, a1, a2, a3, ag, j, hq)
                }
                __builtin_amdgcn_sched_barrier(0);
#pragma unroll
                for (int j = 0; j < 8; ++j) {
                    uint4 hq = H1[j];
                    DOTQ_AG(a0, a1, a2, a3, ag, 8 + j, hq)
                }
                float a  = gate_act((a0 + a1) + (a2 + a3), isg);
                float ai = dpp_bcast<0x00>(a);
                float af = dpp_bcast<0x55>(a);
                float agg= dpp_bcast<0xAA>(a);
                float ao = dpp_bcast<0xFF>(a);
                c1 = fmaf(af, c1, ai * agg);
                float h1n = ao * tanhf_f(c1);            // Y[s-1]
                float hpart = __shfl_xor(h1n, 4);        // partner unit u^1
                if ((q & 7) == 0) h1p[pn][u >> 1] = pack_h2(h1n, hpart);
                if ((q & 3) == 1) h1h[(s - 1) * HID + u] = h1n;
            }
            asm volatile("s_waitcnt lgkmcnt(0)" ::: "memory");
            __builtin_amdgcn_s_barrier();
            asm volatile("" ::: "memory");
        }
    }
}

// ---------------------------------------------------------------------------
// Kernel 3a/3b: column-wise min/max of oldh (64 cols x 8192 rows)
// ---------------------------------------------------------------------------
__global__ __launch_bounds__(256) void k_minmax1(
    const float* __restrict__ oldh, float* __restrict__ pmn, float* __restrict__ pmx)
{
    const int t = threadIdx.x, b = blockIdx.x;
    float vmn = FLT_MAX, vmx = -FLT_MAX;
    for (int i = t; i < 128 * HID; i += 256) {
        float v = oldh[b * 128 * HID + i];
        vmn = fminf(vmn, v); vmx = fmaxf(vmx, v);
    }
    __shared__ float smn[256], smx[256];
    smn[t] = vmn; smx[t] = vmx;
    __syncthreads();
    if (t < 64) {
        float m0 = fminf(fminf(smn[t], smn[t + 64]), fminf(smn[t + 128], smn[t + 192]));
        float m1 = fmaxf(fmaxf(smx[t], smx[t + 64]), fmaxf(smx[t + 128], smx[t + 192]));
        pmn[b * 64 + t] = m0; pmx[b * 64 + t] = m1;
    }
}

__global__ __launch_bounds__(256) void k_minmax2(
    const float* __restrict__ pmn, const float* __restrict__ pmx,
    float* __restrict__ mn, float* __restrict__ mx)
{
    const int t = threadIdx.x, col = t & 63, chunk = t >> 6;
    float vmn = FLT_MAX, vmx = -FLT_MAX;
    for (int r = chunk * 16; r < chunk * 16 + 16; ++r) {
        vmn = fminf(vmn, pmn[r * 64 + col]);
        vmx = fmaxf(vmx, pmx[r * 64 + col]);
    }
    __shared__ float smn[256], smx[256];
    smn[t] = vmn; smx[t] = vmx;
    __syncthreads();
    if (t < 64) {
        mn[t] = fminf(fminf(smn[t], smn[t + 64]), fminf(smn[t + 128], smn[t + 192]));
        mx[t] = fmaxf(fmaxf(smx[t], smx[t + 64]), fmaxf(smx[t + 128], smx[t + 192]));
    }
}

// ---------------------------------------------------------------------------
// Kernel 4: per-row head + HPM MLP fwd + closed-form VJP. 1 wave per row.
// ---------------------------------------------------------------------------
__global__ __launch_bounds__(256) void k_finalize(
    const float* __restrict__ h1h, const float* __restrict__ oldh,
    const float* __restrict__ x,
    const float* __restrict__ Wlin, const float* __restrict__ blin,
    const float* __restrict__ Wh1,  const float* __restrict__ bh1,
    const float* __restrict__ Wh2,  const float* __restrict__ bh2,
    const float* __restrict__ mn,   const float* __restrict__ mx,
    float* __restrict__ dout)
{
    float* out_o = dout;                          // [SEQ][10]
    float* out_F = dout + SEQ * OUTW;             // [SEQ][180]
    float* out_A = dout + SEQ * (OUTW + INW);     // [SEQ][318]

    const int wave = threadIdx.x >> 6, lane = threadIdx.x & 63;
    const int row  = blockIdx.x * 4 + wave;

    __shared__ float Xs[4][XW + 2];
    __shared__ float h1sh[4][HID];

    h1sh[wave][lane] = h1h[row * HID + lane];
    float mnv = mn[lane], mxv = mx[lane];
    Xs[wave][254 + lane] = (oldh[row * HID + lane] - mnv) * frcp(mxv - mnv + 1e-6f);
    Xs[wave][10 + lane]  = 0.0f;
    for (int c = lane; c < INW; c += 64) Xs[wave][74 + c] = x[row * INW + c];
    __syncthreads();

    if (lane < OUTW) {
        float o = blin[lane];
#pragma unroll
        for (int k = 0; k < HID; ++k) o += Wlin[lane * HID + k] * h1sh[wave][k];
        Xs[wave][lane] = o;
        out_o[row * OUTW + lane] = o;
    }
    __syncthreads();

    float z0 = 0.f, z1 = 0.f, s0 = 0.f, s1 = 0.f;
    for (int c = lane; c < XW; c += 64) {
        float xv = Xs[wave][c];
        z0 += xv * Wh1[c];
        z1 += xv * Wh1[XW + c];
    }
    for (int j = lane; j < INW; j += 64) {
        s0 += Wh2[j * 2 + 0];
        s1 += Wh2[j * 2 + 1];
    }
#pragma unroll
    for (int off = 32; off; off >>= 1) {
        z0 += __shfl_xor(z0, off); z1 += __shfl_xor(z1, off);
        s0 += __shfl_xor(s0, off); s1 += __shfl_xor(s1, off);
    }
    const float t0 = tanhf_f(z0 + bh1[0]);
    const float t1 = tanhf_f(z1 + bh1[1]);
    const float a0 = -s0 * (1.0f - t0 * t0);
    const float a1 = -s1 * (1.0f - t1 * t1);

    for (int c = lane; c < INW; c += 64)
        out_F[row * INW + c] = -(t0 * Wh2[c * 2 + 0] + t1 * Wh2[c * 2 + 1] + bh2[c]);
    for (int c = lane; c < XW; c += 64)
        out_A[row * XW + c] = a0 * Wh1[c] + a1 * Wh1[XW + c];
}

// ---------------------------------------------------------------------------
extern "C" void kernel_launch(void* const* d_in, const int* in_sizes, int n_in,
                              void* d_out, int out_size, void* d_ws, size_t ws_size,
                              hipStream_t stream)
{
    const float* input = (const float*)d_in[0];
    const float* Wih0  = (const float*)d_in[1];
    const float* Whh0  = (const float*)d_in[2];
    const float* bih0  = (const float*)d_in[3];
    const float* bhh0  = (const float*)d_in[4];
    const float* Wih1  = (const float*)d_in[5];
    const float* Whh1  = (const float*)d_in[6];
    const float* bih1  = (const float*)d_in[7];
    const float* bhh1  = (const float*)d_in[8];
    const float* Wlin  = (const float*)d_in[9];
    const float* blin  = (const float*)d_in[10];
    const float* Wh1   = (const float*)d_in[11];
    const float* bh1   = (const float*)d_in[12];
    const float* Wh2   = (const float*)d_in[13];
    const float* bh2   = (const float*)d_in[14];

    float* ws   = (float*)d_ws;
    float* pre  = ws;                         // SEQ*G4
    float* oldh = pre  + SEQ * G4;            // SEQ*HID
    float* h1h  = oldh + SEQ * HID;           // SEQ*HID
    float* pmn  = h1h  + SEQ * HID;           // 64*64
    float* pmx  = pmn  + 64 * 64;             // 64*64
    float* mn   = pmx  + 64 * 64;             // 64
    float* mx   = mn   + 64;                  // 64
    uint32* w0h  = (uint32*)(mx + 64);        // G4*32 packed half2
    uint32* w1ah = w0h  + G4 * 32;
    uint32* w1bh = w1ah + G4 * 32;
    float* out  = (float*)d_out;

    hipLaunchKernelGGL(k_packw, dim3(96), dim3(256), 0, stream,
                       Whh0, Wih1, Whh1, w0h, w1ah, w1bh);
    hipLaunchKernelGGL(k_precompute, dim3(SEQ / PRE_TS), dim3(256), 0, stream,
                       input, Wih0, bih0, bhh0, pre);
    hipLaunchKernelGGL(k_lstm_seq, dim3(1), dim3(512), 0, stream,
                       pre, w0h, w1ah, w1bh, bih1, bhh1, oldh, h1h);
    hipLaunchKernelGGL(k_minmax1, dim3(64), dim3(256), 0, stream, oldh, pmn, pmx);
    hipLaunchKernelGGL(k_minmax2, dim3(1), dim3(256), 0, stream, pmn, pmx, mn, mx);
    hipLaunchKernelGGL(k_finalize, dim3(SEQ / 4), dim3(256), 0, stream,
                       h1h, oldh, input, Wlin, blin, Wh1, bh1, Wh2, bh2, mn, mx, out);
}

// Round 14
// 4849.363 us; speedup vs baseline: 1.9493x; 1.3125x over previous
//
#include <hip/hip_runtime.h>
#include <hip/hip_bf16.h>
#include <float.h>

#define SEQ   8192
#define INW   180
#define HID   64
#define G4    256   // 4*HID
#define OUTW  10
#define XW    318   // 10 + 64 + 180 + 64

typedef _Float16 h16x2 __attribute__((ext_vector_type(2)));
typedef unsigned int uint32;

__device__ __forceinline__ float frcp(float x)   { return __builtin_amdgcn_rcpf(x); }
__device__ __forceinline__ float tanhf_f(float x){ return 1.0f - 2.0f * frcp(1.0f + __expf(2.0f * x)); }
__device__ __forceinline__ float gate_act(float x, bool isg) {
    float xx = isg ? 2.0f * x : x;
    float s  = frcp(1.0f + __expf(-xx));
    return isg ? 2.0f * s - 1.0f : s;
}

template<int CTRL>
__device__ __forceinline__ float dpp_mov(float x) {
    return __int_as_float(__builtin_amdgcn_update_dpp(
        0, __float_as_int(x), CTRL, 0xF, 0xF, true));
}
// quad_perm broadcasts / swaps (pure VALU, no LDS):
//   0x00 lane0, 0x55 lane1, 0xAA lane2, 0xFF lane3 of each quad
//   0xB1 = [1,0,3,2] = xor-1 within quad

// v_dot2_f32_f16: acc += a.x*b.x + a.y*b.y  (f32 accumulate, exact products)
__device__ __forceinline__ float fdot2h(uint32 a, uint32 b, float c) {
#if __has_builtin(__builtin_amdgcn_fdot2)
    return __builtin_amdgcn_fdot2(__builtin_bit_cast(h16x2, a),
                                  __builtin_bit_cast(h16x2, b), c, false);
#else
    asm("v_dot2_f32_f16 %0, %1, %2, %3" : "=v"(c) : "v"(a), "v"(b), "0"(c));
    return c;
#endif
}

__device__ __forceinline__ uint32 pack_h2(float lo, float hi) {
    h16x2 h; h.x = (_Float16)lo; h.y = (_Float16)hi;
    return __builtin_bit_cast(uint32, h);
}

// Opaque 16B load: asm volatile result can't be rematerialized, so barriers
// with "memory" clobber can't turn the weights into per-step reloads.
__device__ __forceinline__ uint4 opaque_load4u(const uint32* p) {
    uint4 v;
    asm volatile("global_load_dwordx4 %0, %1, off" : "=v"(v) : "v"(p));
    return v;
}

// ---------------------------------------------------------------------------
// Kernel 0: pack the 3 recurrent matrices to half2 (pairs along K).
// ---------------------------------------------------------------------------
__global__ __launch_bounds__(256) void k_packw(
    const float* __restrict__ Whh0, const float* __restrict__ Wih1,
    const float* __restrict__ Whh1,
    uint32* __restrict__ w0h, uint32* __restrict__ w1ah, uint32* __restrict__ w1bh)
{
    const int gid = blockIdx.x * 256 + threadIdx.x;   // 0 .. 3*8192-1
    const int mat = gid >> 13;
    const int i   = gid & 8191;
    const int r   = i >> 5, k2 = i & 31;
    const float* S = (mat == 0) ? Whh0 : (mat == 1) ? Wih1 : Whh1;
    uint32*      D = (mat == 0) ? w0h  : (mat == 1) ? w1ah : w1bh;
    D[i] = pack_h2(S[r * 64 + 2 * k2], S[r * 64 + 2 * k2 + 1]);
}

// ---------------------------------------------------------------------------
// Kernel 1: pre[s][t] = x[s] @ Wih0[row(t)].T + bih0[row(t)] + bhh0[row(t)]
// row(t) = (t&3)*64 + (t>>2)  — matches q=4u+g mapping in k_lstm_seq
// ---------------------------------------------------------------------------
#define PRE_TS 16
__global__ __launch_bounds__(256) void k_precompute(
    const float* __restrict__ x, const float* __restrict__ Wih0,
    const float* __restrict__ bih0, const float* __restrict__ bhh0,
    float* __restrict__ pre)
{
    __shared__ float xT[INW][PRE_TS];
    const int t  = threadIdx.x;
    const int rr = (t & 3) * 64 + (t >> 2);
    const int s0 = blockIdx.x * PRE_TS;
    for (int i = t; i < PRE_TS * INW; i += 256) {
        int s = i / INW, k = i % INW;
        xT[k][s] = x[s0 * INW + i];
    }
    __syncthreads();
    float acc[PRE_TS];
    const float b = bih0[rr] + bhh0[rr];
#pragma unroll
    for (int s = 0; s < PRE_TS; ++s) acc[s] = b;
    for (int k = 0; k < INW; ++k) {
        float w = Wih0[rr * INW + k];
#pragma unroll
        for (int s = 0; s < PRE_TS; ++s) acc[s] += w * xT[k][s];
    }
#pragma unroll
    for (int s = 0; s < PRE_TS; ++s) pre[(s0 + s) * G4 + t] = acc[s];
}

// 4 fdot2 over one weight quad vs one h quad, 2 accumulators
#define DOTQ2(A0, A1, WQ, HQ)                                \
    A0 = fdot2h((WQ).x, (HQ).x, A0);                         \
    A1 = fdot2h((WQ).y, (HQ).y, A1);                         \
    A0 = fdot2h((WQ).z, (HQ).z, A0);                         \
    A1 = fdot2h((WQ).w, (HQ).w, A1);

// 8-quad dot with 3-quad rotating lookahead staging (<=12 live staging regs).
// Reads stay 1-2 quads ahead of use; sched_barrier(0) stops the scheduler
// from hoisting ALL reads (which would need 32 staging regs and spill).
#define DOT8R(A0, A1, W, HP)                                 \
    {                                                        \
        uint4 hA = (HP)[0], hB = (HP)[1], hC = (HP)[2];      \
        DOTQ2(A0, A1, (W)[0], hA)  hA = (HP)[3];             \
        __builtin_amdgcn_sched_barrier(0);                   \
        DOTQ2(A0, A1, (W)[1], hB)  hB = (HP)[4];             \
        __builtin_amdgcn_sched_barrier(0);                   \
        DOTQ2(A0, A1, (W)[2], hC)  hC = (HP)[5];             \
        __builtin_amdgcn_sched_barrier(0);                   \
        DOTQ2(A0, A1, (W)[3], hA)  hA = (HP)[6];             \
        __builtin_amdgcn_sched_barrier(0);                   \
        DOTQ2(A0, A1, (W)[4], hB)  hB = (HP)[7];             \
        __builtin_amdgcn_sched_barrier(0);                   \
        DOTQ2(A0, A1, (W)[5], hC)                            \
        DOTQ2(A0, A1, (W)[6], hA)                            \
        DOTQ2(A0, A1, (W)[7], hB)                            \
    }

// ---------------------------------------------------------------------------
// Kernel 2: serial 2-layer LSTM, wave-specialized, fp16-dot2 recurrence.
// ONE block, 768 threads (12 waves, 3/SIMD). SEQ+1 barrier intervals
// (R8/R9-verified skew), one s_barrier per interval:
//   t <  256 (q=t):      layer0, s=0..SEQ-1: H0[s+1]=cell(x(s),H0[s],c0)
//                        full Whh0 row (8 fp16-quads = 32 VGPR).
//   t >= 256 (i9=t-256): layer1, s=1..SEQ:  Y[s-1]=cell(H0[s],Y[s-2],c1)
//                        lane-pair matrix split: half0=Wih1 row vs h0,
//                        half1=Whh1 row vs h1 (8 quads = 32 VGPR each);
//                        pair-sum via DPP quad_perm xor1 (no ds_bpermute).
// Register budget engineered for the ~68-VGPR grant this block size gets:
// 32 weights + 12 rotating staging + 2 accums + ~16 misc ~= 62 (R8's 16-reg
// staging windows + 4 accums pegged the cap and spilled -> 1450cyc/step).
// ---------------------------------------------------------------------------
__global__ __launch_bounds__(768, 1)
void k_lstm_seq(
    const float* __restrict__ pre,
    const uint32* __restrict__ w0h,    // [G4][32] packed Whh0
    const uint32* __restrict__ w1ah,   // [G4][32] packed Wih1
    const uint32* __restrict__ w1bh,   // [G4][32] packed Whh1
    const float* __restrict__ bih1, const float* __restrict__ bhh1,
    float* __restrict__ oldh, float* __restrict__ h1h)
{
    const int t = threadIdx.x;

    __shared__ __attribute__((aligned(16))) uint32 h0p[2][32];
    __shared__ __attribute__((aligned(16))) uint32 h1p[2][32];
    if (t < 32) { h0p[0][t] = 0u; h0p[1][t] = 0u; h1p[0][t] = 0u; h1p[1][t] = 0u; }
    if (t < 64) oldh[t] = 0.0f;
    __syncthreads();

    if (t < 256) {
        // ================= layer-0: full Whh0 row =================
        const int q = t, g = q & 3, u = q >> 2, r = g * 64 + u;
        const bool isg = (g == 2);

        uint4 w[8];
        {
            const uint32* W = w0h + r * 32;
#pragma unroll
            for (int j = 0; j < 8; ++j) w[j] = opaque_load4u(W + 4 * j);
            asm volatile("s_waitcnt vmcnt(0)" ::: "memory");
        }
        float c0 = 0.f;
        float preval = pre[q];
        for (int s = 0; s <= SEQ; ++s) {
            if (s < SEQ) {
                const int p = s & 1, pn = p ^ 1;
                const int sn = (s + 1 < SEQ) ? (s + 1) : s;
                float prenext = pre[sn * G4 + q];

                const uint4* Hp = (const uint4*)&h0p[p][0];
                float a0 = preval, a1 = 0.f;
                DOT8R(a0, a1, w, Hp)
                float a  = gate_act(a0 + a1, isg);
                float ai = dpp_mov<0x00>(a);
                float af = dpp_mov<0x55>(a);
                float ag = dpp_mov<0xAA>(a);
                float ao = dpp_mov<0xFF>(a);
                c0 = fmaf(af, c0, ai * ag);
                float h0n = ao * tanhf_f(c0);
                float hpart = __shfl_xor(h0n, 4);        // partner unit u^1
                if ((q & 7) == 0) h0p[pn][u >> 1] = pack_h2(h0n, hpart);
                if ((q & 3) == 1 && s + 1 < SEQ) oldh[(s + 1) * HID + u] = h0n;
                preval = prenext;
            }
            asm volatile("s_waitcnt lgkmcnt(0)" ::: "memory");
            __builtin_amdgcn_s_barrier();
            asm volatile("" ::: "memory");
        }
    } else {
        // ================= layer-1: lane-pair matrix split =================
        const int i9   = t - 256;       // 0..511
        const int q    = i9 >> 1;       // row 0..255
        const int half = i9 & 1;        // 0: Wih1 vs h0, 1: Whh1 vs h1
        const int g    = q & 3, u = q >> 2, r = g * 64 + u;
        const int lane = t & 63;
        const bool isg = (g == 2);
        const bool hi4 = (lane & 4) != 0;

        uint4 w[8];
        {
            const uint32* Wb = half ? (w1bh + r * 32) : (w1ah + r * 32);
#pragma unroll
            for (int j = 0; j < 8; ++j) w[j] = opaque_load4u(Wb + 4 * j);
            asm volatile("s_waitcnt vmcnt(0)" ::: "memory");
        }
        const float b1 = bih1[r] + bhh1[r];
        float c1 = 0.f;
        for (int s = 0; s <= SEQ; ++s) {
            if (s >= 1) {
                const int p = s & 1, pn = p ^ 1;

                const uint4* Hp = half ? (const uint4*)&h1p[p][0]
                                       : (const uint4*)&h0p[p][0];
                float a0 = half ? 0.f : b1, a1 = 0.f;
                DOT8R(a0, a1, w, Hp)
                float ap = a0 + a1;
                ap += dpp_mov<0xB1>(ap);                 // pair sum (xor1, DPP)
                float a  = gate_act(ap, isg);
                float p0 = dpp_mov<0x00>(a), p2 = dpp_mov<0xAA>(a);
                float s0 = __shfl_xor(p0, 4), s2 = __shfl_xor(p2, 4);
                float i_ = hi4 ? s0 : p0, f_ = hi4 ? s2 : p2;
                float g_ = hi4 ? p0 : s0, o_ = hi4 ? p2 : s2;
                c1 = fmaf(f_, c1, i_ * g_);
                float h1n = o_ * tanhf_f(c1);            // Y[s-1]
                float hpart = __shfl_xor(h1n, 8);        // partner unit u^1
                if ((i9 & 15) == 0) h1p[pn][u >> 1] = pack_h2(h1n, hpart);
                if ((i9 & 7) == 2) h1h[(s - 1) * HID + u] = h1n;
            }
            asm volatile("s_waitcnt lgkmcnt(0)" ::: "memory");
            __builtin_amdgcn_s_barrier();
            asm volatile("" ::: "memory");
        }
    }
}

// ---------------------------------------------------------------------------
// Kernel 3a/3b: column-wise min/max of oldh (64 cols x 8192 rows)
// ---------------------------------------------------------------------------
__global__ __launch_bounds__(256) void k_minmax1(
    const float* __restrict__ oldh, float* __restrict__ pmn, float* __restrict__ pmx)
{
    const int t = threadIdx.x, b = blockIdx.x;
    float vmn = FLT_MAX, vmx = -FLT_MAX;
    for (int i = t; i < 128 * HID; i += 256) {
        float v = oldh[b * 128 * HID + i];
        vmn = fminf(vmn, v); vmx = fmaxf(vmx, v);
    }
    __shared__ float smn[256], smx[256];
    smn[t] = vmn; smx[t] = vmx;
    __syncthreads();
    if (t < 64) {
        float m0 = fminf(fminf(smn[t], smn[t + 64]), fminf(smn[t + 128], smn[t + 192]));
        float m1 = fmaxf(fmaxf(smx[t], smx[t + 64]), fmaxf(smx[t + 128], smx[t + 192]));
        pmn[b * 64 + t] = m0; pmx[b * 64 + t] = m1;
    }
}

__global__ __launch_bounds__(256) void k_minmax2(
    const float* __restrict__ pmn, const float* __restrict__ pmx,
    float* __restrict__ mn, float* __restrict__ mx)
{
    const int t = threadIdx.x, col = t & 63, chunk = t >> 6;
    float vmn = FLT_MAX, vmx = -FLT_MAX;
    for (int r = chunk * 16; r < chunk * 16 + 16; ++r) {
        vmn = fminf(vmn, pmn[r * 64 + col]);
        vmx = fmaxf(vmx, pmx[r * 64 + col]);
    }
    __shared__ float smn[256], smx[256];
    smn[t] = vmn; smx[t] = vmx;
    __syncthreads();
    if (t < 64) {
        mn[t] = fminf(fminf(smn[t], smn[t + 64]), fminf(smn[t + 128], smn[t + 192]));
        mx[t] = fmaxf(fmaxf(smx[t], smx[t + 64]), fmaxf(smx[t + 128], smx[t + 192]));
    }
}

// ---------------------------------------------------------------------------
// Kernel 4: per-row head + HPM MLP fwd + closed-form VJP. 1 wave per row.
// ---------------------------------------------------------------------------
__global__ __launch_bounds__(256) void k_finalize(
    const float* __restrict__ h1h, const float* __restrict__ oldh,
    const float* __restrict__ x,
    const float* __restrict__ Wlin, const float* __restrict__ blin,
    const float* __restrict__ Wh1,  const float* __restrict__ bh1,
    const float* __restrict__ Wh2,  const float* __restrict__ bh2,
    const float* __restrict__ mn,   const float* __restrict__ mx,
    float* __restrict__ dout)
{
    float* out_o = dout;                          // [SEQ][10]
    float* out_F = dout + SEQ * OUTW;             // [SEQ][180]
    float* out_A = dout + SEQ * (OUTW + INW);     // [SEQ][318]

    const int wave = threadIdx.x >> 6, lane = threadIdx.x & 63;
    const int row  = blockIdx.x * 4 + wave;

    __shared__ float Xs[4][XW + 2];
    __shared__ float h1sh[4][HID];

    h1sh[wave][lane] = h1h[row * HID + lane];
    float mnv = mn[lane], mxv = mx[lane];
    Xs[wave][254 + lane] = (oldh[row * HID + lane] - mnv) * frcp(mxv - mnv + 1e-6f);
    Xs[wave][10 + lane]  = 0.0f;
    for (int c = lane; c < INW; c += 64) Xs[wave][74 + c] = x[row * INW + c];
    __syncthreads();

    if (lane < OUTW) {
        float o = blin[lane];
#pragma unroll
        for (int k = 0; k < HID; ++k) o += Wlin[lane * HID + k] * h1sh[wave][k];
        Xs[wave][lane] = o;
        out_o[row * OUTW + lane] = o;
    }
    __syncthreads();

    float z0 = 0.f, z1 = 0.f, s0 = 0.f, s1 = 0.f;
    for (int c = lane; c < XW; c += 64) {
        float xv = Xs[wave][c];
        z0 += xv * Wh1[c];
        z1 += xv * Wh1[XW + c];
    }
    for (int j = lane; j < INW; j += 64) {
        s0 += Wh2[j * 2 + 0];
        s1 += Wh2[j * 2 + 1];
    }
#pragma unroll
    for (int off = 32; off; off >>= 1) {
        z0 += __shfl_xor(z0, off); z1 += __shfl_xor(z1, off);
        s0 += __shfl_xor(s0, off); s1 += __shfl_xor(s1, off);
    }
    const float t0 = tanhf_f(z0 + bh1[0]);
    const float t1 = tanhf_f(z1 + bh1[1]);
    const float a0 = -s0 * (1.0f - t0 * t0);
    const float a1 = -s1 * (1.0f - t1 * t1);

    for (int c = lane; c < INW; c += 64)
        out_F[row * INW + c] = -(t0 * Wh2[c * 2 + 0] + t1 * Wh2[c * 2 + 1] + bh2[c]);
    for (int c = lane; c < XW; c += 64)
        out_A[row * XW + c] = a0 * Wh1[c] + a1 * Wh1[XW + c];
}

// ---------------------------------------------------------------------------
extern "C" void kernel_launch(void* const* d_in, const int* in_sizes, int n_in,
                              void* d_out, int out_size, void* d_ws, size_t ws_size,
                              hipStream_t stream)
{
    const float* input = (const float*)d_in[0];
    const float* Wih0  = (const float*)d_in[1];
    const float* Whh0  = (const float*)d_in[2];
    const float* bih0  = (const float*)d_in[3];
    const float* bhh0  = (const float*)d_in[4];
    const float* Wih1  = (const float*)d_in[5];
    const float* Whh1  = (const float*)d_in[6];
    const float* bih1  = (const float*)d_in[7];
    const float* bhh1  = (const float*)d_in[8];
    const float* Wlin  = (const float*)d_in[9];
    const float* blin  = (const float*)d_in[10];
    const float* Wh1   = (const float*)d_in[11];
    const float* bh1   = (const float*)d_in[12];
    const float* Wh2   = (const float*)d_in[13];
    const float* bh2   = (const float*)d_in[14];

    float* ws   = (float*)d_ws;
    float* pre  = ws;                         // SEQ*G4
    float* oldh = pre  + SEQ * G4;            // SEQ*HID
    float* h1h  = oldh + SEQ * HID;           // SEQ*HID
    float* pmn  = h1h  + SEQ * HID;           // 64*64
    float* pmx  = pmn  + 64 * 64;             // 64*64
    float* mn   = pmx  + 64 * 64;             // 64
    float* mx   = mn   + 64;                  // 64
    uint32* w0h  = (uint32*)(mx + 64);        // G4*32 packed half2
    uint32* w1ah = w0h  + G4 * 32;
    uint32* w1bh = w1ah + G4 * 32;
    float* out  = (float*)d_out;

    hipLaunchKernelGGL(k_packw, dim3(96), dim3(256), 0, stream,
                       Whh0, Wih1, Whh1, w0h, w1ah, w1bh);
    hipLaunchKernelGGL(k_precompute, dim3(SEQ / PRE_TS), dim3(256), 0, stream,
                       input, Wih0, bih0, bhh0, pre);
    hipLaunchKernelGGL(k_lstm_seq, dim3(1), dim3(768), 0, stream,
                       pre, w0h, w1ah, w1bh, bih1, bhh1, oldh, h1h);
    hipLaunchKernelGGL(k_minmax1, dim3(64), dim3(256), 0, stream, oldh, pmn, pmx);
    hipLaunchKernelGGL(k_minmax2, dim3(1), dim3(256), 0, stream, pmn, pmx, mn, mx);
    hipLaunchKernelGGL(k_finalize, dim3(SEQ / 4), dim3(256), 0, stream,
                       h1h, oldh, input, Wlin, blin, Wh1, bh1, Wh2, bh2, mn, mx, out);
}